// Round 1
// baseline (533.334 us; speedup 1.0000x reference)
//
#include <hip/hip_runtime.h>
#include <cstdint>
#include <cstddef>

// Problem constants (from reference)
#define BB 96
#define SS 4
#define TT 16
#define KK 36
#define VDIM 1024
#define QDIM 512
#define HH 512

typedef __attribute__((ext_vector_type(8))) short short8;
typedef __attribute__((ext_vector_type(4))) float f32x4;

static __device__ __forceinline__ unsigned short f2bf(float f) {
    union { float f; unsigned u; } v; v.f = f;
    unsigned u = v.u;
    u += 0x7FFFu + ((u >> 16) & 1u);   // RNE
    return (unsigned short)(u >> 16);
}

// ---------------------------------------------------------------------------
// Kernel 0: W1v (rows 0..1023 of w1, fp32 [1536][512]) -> bf16 transposed
// w1vT[c][k], c<512, k<1024 (row stride 1024)
// ---------------------------------------------------------------------------
__global__ __launch_bounds__(256) void prep_w1T(const float* __restrict__ w1,
                                                unsigned short* __restrict__ w1vT) {
    int idx = blockIdx.x * 256 + threadIdx.x;      // 0 .. 512*1024-1
    int k = idx & 1023;
    int c = idx >> 10;
    w1vT[idx] = f2bf(w1[(size_t)k * HH + c]);
}

// ---------------------------------------------------------------------------
// Kernel 1: qp[n][h] = b1[h] + sum_d q[n][d] * w1[1024+d][h]   (fp32 exact)
// block = 256 threads, 32 rows per block
// ---------------------------------------------------------------------------
__global__ __launch_bounds__(256) void qproj_kernel(const float* __restrict__ q,
                                                    const float* __restrict__ w1,
                                                    const float* __restrict__ b1,
                                                    float* __restrict__ qp) {
    __shared__ float qs[32 * QDIM];   // 64 KB
    int tid = threadIdx.x;
    int n0 = blockIdx.x * 32;
    // load 32 rows x 512 floats, coalesced float4
    const float4* src = (const float4*)(q + (size_t)n0 * QDIM);
    float4* dst = (float4*)qs;
    for (int i = tid; i < 32 * QDIM / 4; i += 256) dst[i] = src[i];
    __syncthreads();

    int cg = tid & 127;       // 128 col groups of 4
    int h  = cg * 4;
    int rh = tid >> 7;        // 0..1 -> rows rh*16 .. +15
    int r0 = rh * 16;

    float4 acc[16];
    float4 bv = *(const float4*)(b1 + h);
#pragma unroll
    for (int r = 0; r < 16; ++r) acc[r] = bv;

    for (int d = 0; d < QDIM; d += 4) {
        float4 wa = *(const float4*)(w1 + (size_t)(VDIM + d + 0) * HH + h);
        float4 wb = *(const float4*)(w1 + (size_t)(VDIM + d + 1) * HH + h);
        float4 wc = *(const float4*)(w1 + (size_t)(VDIM + d + 2) * HH + h);
        float4 wd = *(const float4*)(w1 + (size_t)(VDIM + d + 3) * HH + h);
#pragma unroll
        for (int r = 0; r < 16; ++r) {
            float4 qv = *(const float4*)&qs[(r0 + r) * QDIM + d];
            acc[r].x += qv.x * wa.x + qv.y * wb.x + qv.z * wc.x + qv.w * wd.x;
            acc[r].y += qv.x * wa.y + qv.y * wb.y + qv.z * wc.y + qv.w * wd.y;
            acc[r].z += qv.x * wa.z + qv.y * wb.z + qv.z * wc.z + qv.w * wd.z;
            acc[r].w += qv.x * wa.w + qv.y * wb.w + qv.z * wc.w + qv.w * wd.w;
        }
    }
#pragma unroll
    for (int r = 0; r < 16; ++r)
        *(float4*)(qp + (size_t)(n0 + r0 + r) * HH + h) = acc[r];
}

// ---------------------------------------------------------------------------
// Kernel 2: main GEMM. A = v as (M,1024) fp32 -> bf16, B = w1vT (bf16).
// Per block: 64 rows x 512 cols, K-loop over 1024 in BK=64 chunks.
// 8 waves = 4(M) x 2(N). Wave: 16 rows x 256 cols = 16 MFMA tiles 16x16x32.
// Epilogue: joint = acc + qp[n][c]; logits[m] = sum_c relu(joint)*w2[c] + b2.
// ---------------------------------------------------------------------------
__global__ __launch_bounds__(512, 2) void main_gemm(const float* __restrict__ v,
                                                    const unsigned short* __restrict__ w1vT,
                                                    const float* __restrict__ qp,
                                                    const float* __restrict__ w2,
                                                    const float* __restrict__ b2,
                                                    float* __restrict__ logits) {
    __shared__ __align__(16) unsigned short At[64][72];    // 9.2 KB (pad 8 -> 2-way max)
    __shared__ __align__(16) unsigned short Bt[512][72];   // 73.7 KB, Bt[c][k]
    __shared__ float w2s[HH];
    __shared__ float fl2[2][64];

    int tid  = threadIdx.x;
    int lane = tid & 63;
    int wid  = tid >> 6;
    int wm   = wid >> 1;       // 0..3
    int wn   = wid & 1;        // 0..1
    int m0   = blockIdx.x * 64;

    w2s[tid < HH ? tid : 0] = w2[tid < HH ? tid : 0];  // tid always < 512
    f32x4 acc[16];
#pragma unroll
    for (int t = 0; t < 16; ++t) acc[t] = (f32x4){0.f, 0.f, 0.f, 0.f};

    int lr = lane & 15;
    int lg = lane >> 4;

    for (int k0 = 0; k0 < VDIM; k0 += 64) {
        // ---- stage A: 64 rows x 64 k fp32 -> bf16 ----
        {
            int r  = tid >> 3;
            int cs = (tid & 7) * 8;
            const float* srcp = v + (size_t)(m0 + r) * VDIM + k0 + cs;
            float4 f0 = *(const float4*)(srcp);
            float4 f1 = *(const float4*)(srcp + 4);
            unsigned short tmp[8] = {f2bf(f0.x), f2bf(f0.y), f2bf(f0.z), f2bf(f0.w),
                                     f2bf(f1.x), f2bf(f1.y), f2bf(f1.z), f2bf(f1.w)};
            *(short8*)&At[r][cs] = *(const short8*)tmp;
        }
        // ---- stage B: 512 cols x 64 k bf16 ----
#pragma unroll
        for (int p = 0; p < 8; ++p) {
            int c  = (tid >> 3) + p * 64;
            int ks = (tid & 7) * 8;
            short8 bv = *(const short8*)(w1vT + (size_t)c * VDIM + k0 + ks);
            *(short8*)&Bt[c][ks] = bv;
        }
        __syncthreads();

#pragma unroll
        for (int kk = 0; kk < 64; kk += 32) {
            short8 af = *(const short8*)&At[wm * 16 + lr][kk + lg * 8];
#pragma unroll
            for (int t = 0; t < 16; ++t) {
                int c = wn * 256 + t * 16 + lr;
                short8 bf = *(const short8*)&Bt[c][kk + lg * 8];
                acc[t] = __builtin_amdgcn_mfma_f32_16x16x32_bf16(af, bf, acc[t], 0, 0, 0);
            }
        }
        __syncthreads();
    }

    // ---- epilogue: add qp, relu, dot with w2, reduce to logits ----
    float b2v = b2[0];
    int ns[4];
#pragma unroll
    for (int r = 0; r < 4; ++r) {
        int row = wm * 16 + lg * 4 + r;
        ns[r] = (m0 + row) / KK;
    }
    float part[4] = {0.f, 0.f, 0.f, 0.f};
#pragma unroll
    for (int t = 0; t < 16; ++t) {
        int c = wn * 256 + t * 16 + lr;
        float w2v = w2s[c];
#pragma unroll
        for (int r = 0; r < 4; ++r) {
            float pre = acc[t][r] + qp[(size_t)ns[r] * HH + c];
            part[r] += fmaxf(pre, 0.f) * w2v;
        }
    }
#pragma unroll
    for (int r = 0; r < 4; ++r) {
        float s = part[r];
        s += __shfl_xor(s, 1, 64);
        s += __shfl_xor(s, 2, 64);
        s += __shfl_xor(s, 4, 64);
        s += __shfl_xor(s, 8, 64);
        if (lr == 0) fl2[wn][wm * 16 + lg * 4 + r] = s;
    }
    __syncthreads();
    if (tid < 64) logits[m0 + tid] = fl2[0][tid] + fl2[1][tid] + b2v;
}

// ---------------------------------------------------------------------------
// Kernel 3: masked softmax. One wave per (b,s,t). w_k = m_k e^{l_k}/sum m_j e^{l_j}
// ---------------------------------------------------------------------------
__global__ __launch_bounds__(256) void softmax_kernel(const float* __restrict__ logits,
                                                      const float* __restrict__ box_mask,
                                                      const int* __restrict__ tags,
                                                      float* __restrict__ out) {
    int lane = threadIdx.x & 63;
    int g = blockIdx.x * 4 + (threadIdx.x >> 6);   // 0 .. B*S*T-1
    int t   = g & (TT - 1);
    int row = g >> 4;            // b*S + s
    int b   = row >> 2;

    int base = row * TT;
    int length = 0;
#pragma unroll
    for (int i = 0; i < TT; ++i) length += tags[base + i];

    int s = 0;
    for (int j = lane; j < base; j += 64) s += tags[j];
#pragma unroll
    for (int off = 32; off >= 1; off >>= 1) s += __shfl_xor(s, off, 64);
    int start = s;

    int k = lane;
    bool kv = k < KK;
    float mval = kv ? box_mask[b * KK + k] : 0.f;
    bool act = kv && (mval != 0.f);

    float l = 0.f;
    if (act && t < length) l = logits[(size_t)(start + t) * KK + k];

    float lm = act ? l : -1e30f;
#pragma unroll
    for (int off = 32; off >= 1; off >>= 1) lm = fmaxf(lm, __shfl_xor(lm, off, 64));

    float e = act ? expf(l - lm) : 0.f;
    float se = e;
#pragma unroll
    for (int off = 32; off >= 1; off >>= 1) se += __shfl_xor(se, off, 64);

    if (kv) out[(size_t)g * KK + k] = e / se;
}

// ---------------------------------------------------------------------------
extern "C" void kernel_launch(void* const* d_in, const int* in_sizes, int n_in,
                              void* d_out, int out_size, void* d_ws, size_t ws_size,
                              hipStream_t stream) {
    const float* v        = (const float*)d_in[0];
    const float* q        = (const float*)d_in[1];
    const float* box_mask = (const float*)d_in[2];
    const int*   tags     = (const int*)d_in[3];
    const float* w1       = (const float*)d_in[4];
    const float* b1       = (const float*)d_in[5];
    const float* w2       = (const float*)d_in[6];
    const float* b2       = (const float*)d_in[7];

    int Nrows = in_sizes[0] / (KK * VDIM);     // 3264
    int M     = Nrows * KK;                    // 117504

    unsigned short* w1vT = (unsigned short*)d_ws;                       // 1 MB
    float* qp     = (float*)((char*)d_ws + (1 << 20));                  // 6.7 MB
    float* logits = (float*)((char*)d_ws + (1 << 20) + (size_t)Nrows * HH * 4);
    float* out    = (float*)d_out;

    hipLaunchKernelGGL(prep_w1T, dim3((HH * VDIM) / 256), dim3(256), 0, stream, w1, w1vT);
    hipLaunchKernelGGL(qproj_kernel, dim3(Nrows / 32), dim3(256), 0, stream, q, w1, b1, qp);
    hipLaunchKernelGGL(main_gemm, dim3(M / 64), dim3(512), 0, stream,
                       v, w1vT, qp, w2, b2, logits);
    hipLaunchKernelGGL(softmax_kernel, dim3((BB * SS * TT) / 4), dim3(256), 0, stream,
                       logits, box_mask, tags, out);
}

// Round 2
// 468.158 us; speedup vs baseline: 1.1392x; 1.1392x over previous
//
#include <hip/hip_runtime.h>
#include <cstdint>
#include <cstddef>

#define BB 96
#define SS 4
#define TT 16
#define KK 36
#define VDIM 1024
#define QDIM 512
#define HH 512
#define NROWS 3264
#define MM (NROWS * KK)   // 117504

typedef __attribute__((ext_vector_type(8))) short short8;
typedef __attribute__((ext_vector_type(4))) float f32x4;

static __device__ __forceinline__ unsigned short f2bf(float f) {
    union { float f; unsigned u; } v; v.f = f;
    unsigned u = v.u;
    u += 0x7FFFu + ((u >> 16) & 1u);   // RNE
    return (unsigned short)(u >> 16);
}

__device__ __forceinline__ void gload_lds16(const void* g, void* l) {
    __builtin_amdgcn_global_load_lds(
        (const __attribute__((address_space(1))) unsigned int*)g,
        (__attribute__((address_space(3))) unsigned int*)l, 16, 0, 0);
}

// ---------------------------------------------------------------------------
// Kernel 0: W1v (rows 0..1023 of w1, fp32 [1536][512]) -> bf16 transposed
// w1vT[c][k], c<512, k<1024
// ---------------------------------------------------------------------------
__global__ __launch_bounds__(256) void prep_w1T(const float* __restrict__ w1,
                                                unsigned short* __restrict__ w1vT) {
    int idx = blockIdx.x * 256 + threadIdx.x;
    int k = idx & 1023;
    int c = idx >> 10;
    w1vT[idx] = f2bf(w1[(size_t)k * HH + c]);
}

// ---------------------------------------------------------------------------
// Kernel 1: per-(b,s) segment starts/lengths via LDS scan (one block)
// ---------------------------------------------------------------------------
__global__ __launch_bounds__(512) void starts_kernel(const int* __restrict__ tags,
                                                     int* __restrict__ starts,
                                                     int* __restrict__ lengths) {
    __shared__ int sl[BB * SS];
    int tid = threadIdx.x;
    int len = 0;
    if (tid < BB * SS) {
#pragma unroll
        for (int i = 0; i < TT; ++i) len += tags[tid * TT + i];
        sl[tid] = len;
    }
    __syncthreads();
    for (int off = 1; off < BB * SS; off <<= 1) {
        int v = 0;
        if (tid < BB * SS && tid >= off) v = sl[tid - off];
        __syncthreads();
        if (tid < BB * SS) sl[tid] += v;
        __syncthreads();
    }
    if (tid < BB * SS) { starts[tid] = sl[tid] - len; lengths[tid] = len; }
}

// ---------------------------------------------------------------------------
// Kernel 2: qp[n][h] = b1[h] + sum_d q[n][d] * w1[1024+d][h]  (fp32 exact)
// 16 rows / block, grid = NROWS/16 = 204
// ---------------------------------------------------------------------------
__global__ __launch_bounds__(256) void qproj_kernel(const float* __restrict__ q,
                                                    const float* __restrict__ w1,
                                                    const float* __restrict__ b1,
                                                    float* __restrict__ qp) {
    __shared__ float qs[16 * QDIM];   // 32 KB
    int tid = threadIdx.x;
    int n0 = blockIdx.x * 16;
    const float4* src = (const float4*)(q + (size_t)n0 * QDIM);
    float4* dst = (float4*)qs;
    for (int i = tid; i < 16 * QDIM / 4; i += 256) dst[i] = src[i];
    __syncthreads();

    int cg = tid & 127;
    int h  = cg * 4;
    int rh = tid >> 7;       // 0..1
    int r0 = rh * 8;

    float4 acc[8];
    float4 bv = *(const float4*)(b1 + h);
#pragma unroll
    for (int r = 0; r < 8; ++r) acc[r] = bv;

    for (int d = 0; d < QDIM; d += 4) {
        float4 wa = *(const float4*)(w1 + (size_t)(VDIM + d + 0) * HH + h);
        float4 wb = *(const float4*)(w1 + (size_t)(VDIM + d + 1) * HH + h);
        float4 wc = *(const float4*)(w1 + (size_t)(VDIM + d + 2) * HH + h);
        float4 wd = *(const float4*)(w1 + (size_t)(VDIM + d + 3) * HH + h);
#pragma unroll
        for (int r = 0; r < 8; ++r) {
            float4 qv = *(const float4*)&qs[(r0 + r) * QDIM + d];
            acc[r].x += qv.x * wa.x + qv.y * wb.x + qv.z * wc.x + qv.w * wd.x;
            acc[r].y += qv.x * wa.y + qv.y * wb.y + qv.z * wc.y + qv.w * wd.y;
            acc[r].z += qv.x * wa.z + qv.y * wb.z + qv.z * wc.z + qv.w * wd.z;
            acc[r].w += qv.x * wa.w + qv.y * wb.w + qv.z * wc.w + qv.w * wd.w;
        }
    }
#pragma unroll
    for (int r = 0; r < 8; ++r)
        *(float4*)(qp + (size_t)(n0 + r0 + r) * HH + h) = acc[r];
}

// ---------------------------------------------------------------------------
// Kernel 3: main GEMM. BM=64, BN=512 (full H), BK=32, double-buffered,
// 256 threads = 4 waves (1M x 4N), wave tile 64x128.
// A: reg-staged fp32->bf16, XOR-swizzled ds_write. B: global_load_lds with
// pre-swizzled global source. 2-phase pipeline, one barrier per K-step.
// Epilogue: relu(acc + qp) . w2 reduced to logits.
// ---------------------------------------------------------------------------
__global__ __launch_bounds__(256, 2) void main_gemm(const float* __restrict__ v,
                                                    const unsigned short* __restrict__ w1vT,
                                                    const float* __restrict__ qp,
                                                    const float* __restrict__ w2,
                                                    float* __restrict__ logits) {
    __shared__ __align__(16) unsigned short At[2][64][32];    // 8 KB
    __shared__ __align__(16) unsigned short Bt[2][512][32];   // 64 KB
    __shared__ float fl[4][64];

    int tid  = threadIdx.x;
    int lane = tid & 63;
    int wid  = tid >> 6;     // 0..3 = wn
    int wn   = wid;
    int m0   = blockIdx.x * 64;
    int lr   = lane & 15;
    int lg   = lane >> 4;

    // A staging: thread -> row ar, granule ag (8 cols)
    int ar = tid >> 2;
    int ag = tid & 3;
    const float* a_src = v + (size_t)(m0 + ar) * VDIM + ag * 8;
    int a_phys = (ag ^ (ar & 3)) * 8;

    // B staging: 8 chunks per wave, 1 KB each; pre-swizzled global source
    const unsigned short* b_src[8];
#pragma unroll
    for (int i = 0; i < 8; ++i) {
        int ci = wid * 8 + i;
        int c  = ci * 16 + (lane >> 2);
        int gp = lane & 3;
        int gl = gp ^ (c & 3);
        b_src[i] = w1vT + (size_t)c * VDIM + gl * 8;
    }

    f32x4 acc[4][8];
#pragma unroll
    for (int mt = 0; mt < 4; ++mt)
#pragma unroll
        for (int nt = 0; nt < 8; ++nt) acc[mt][nt] = (f32x4){0.f, 0.f, 0.f, 0.f};

    // ---- prologue: stage K-step 0 into buf 0 ----
    {
        float4 a0 = *(const float4*)(a_src);
        float4 a1 = *(const float4*)(a_src + 4);
#pragma unroll
        for (int i = 0; i < 8; ++i)
            gload_lds16(b_src[i], &Bt[0][(wid * 8 + i) * 16][0]);
        unsigned short tmp[8] = {f2bf(a0.x), f2bf(a0.y), f2bf(a0.z), f2bf(a0.w),
                                 f2bf(a1.x), f2bf(a1.y), f2bf(a1.z), f2bf(a1.w)};
        *(short8*)&At[0][ar][a_phys] = *(const short8*)tmp;
    }
    __syncthreads();

    int buf = 0;
#pragma unroll 2
    for (int it = 0; it < 32; ++it) {
        int k0n = (it + 1) * 32;
        float4 a0n, a1n;
        if (it < 31) {
            // issue next-tile loads early (latency hides under MFMA)
            a0n = *(const float4*)(a_src + k0n);
            a1n = *(const float4*)(a_src + k0n + 4);
#pragma unroll
            for (int i = 0; i < 8; ++i)
                gload_lds16(b_src[i] + k0n, &Bt[buf ^ 1][(wid * 8 + i) * 16][0]);
        }
        // compute current tile
        short8 af[4], bf[8];
#pragma unroll
        for (int mt = 0; mt < 4; ++mt) {
            int row = mt * 16 + lr;
            af[mt] = *(const short8*)&At[buf][row][(lg ^ (row & 3)) * 8];
        }
#pragma unroll
        for (int nt = 0; nt < 8; ++nt) {
            int c = wn * 128 + nt * 16 + lr;
            bf[nt] = *(const short8*)&Bt[buf][c][(lg ^ (c & 3)) * 8];
        }
#pragma unroll
        for (int mt = 0; mt < 4; ++mt)
#pragma unroll
            for (int nt = 0; nt < 8; ++nt)
                acc[mt][nt] = __builtin_amdgcn_mfma_f32_16x16x32_bf16(af[mt], bf[nt],
                                                                      acc[mt][nt], 0, 0, 0);
        if (it < 31) {
            unsigned short tmp[8] = {f2bf(a0n.x), f2bf(a0n.y), f2bf(a0n.z), f2bf(a0n.w),
                                     f2bf(a1n.x), f2bf(a1n.y), f2bf(a1n.z), f2bf(a1n.w)};
            *(short8*)&At[buf ^ 1][ar][a_phys] = *(const short8*)tmp;
        }
        __syncthreads();
        buf ^= 1;
    }

    // ---- epilogue: relu(acc + qp) . w2 -> logits (b2 cancels in softmax) ----
    float part[4][4] = {{0.f}};
#pragma unroll
    for (int nt = 0; nt < 8; ++nt) {
        int c = wn * 128 + nt * 16 + lr;
        float w2v = w2[c];
#pragma unroll
        for (int mt = 0; mt < 4; ++mt)
#pragma unroll
            for (int r = 0; r < 4; ++r) {
                int row = mt * 16 + lg * 4 + r;
                int n = (m0 + row) / KK;
                float pre = acc[mt][nt][r] + qp[(size_t)n * HH + c];
                part[mt][r] += fmaxf(pre, 0.f) * w2v;
            }
    }
#pragma unroll
    for (int mt = 0; mt < 4; ++mt)
#pragma unroll
        for (int r = 0; r < 4; ++r) {
            float s = part[mt][r];
            s += __shfl_xor(s, 1, 64);
            s += __shfl_xor(s, 2, 64);
            s += __shfl_xor(s, 4, 64);
            s += __shfl_xor(s, 8, 64);
            if (lr == 0) fl[wn][mt * 16 + lg * 4 + r] = s;
        }
    __syncthreads();
    if (tid < 64) logits[m0 + tid] = fl[0][tid] + fl[1][tid] + fl[2][tid] + fl[3][tid];
}

// ---------------------------------------------------------------------------
// Kernel 4: masked softmax. One wave per (b,s,t).
// ---------------------------------------------------------------------------
__global__ __launch_bounds__(256) void softmax_kernel(const float* __restrict__ logits,
                                                      const float* __restrict__ box_mask,
                                                      const int* __restrict__ starts,
                                                      const int* __restrict__ lengths,
                                                      float* __restrict__ out) {
    int lane = threadIdx.x & 63;
    int g = blockIdx.x * 4 + (threadIdx.x >> 6);   // 0 .. B*S*T-1
    int t   = g & (TT - 1);
    int row = g >> 4;
    int b   = row >> 2;

    int length = lengths[row];
    int start  = starts[row];

    int k = lane;
    bool kv = k < KK;
    float mval = kv ? box_mask[b * KK + k] : 0.f;
    bool act = kv && (mval != 0.f);

    float l = 0.f;
    if (act && t < length) l = logits[(size_t)(start + t) * KK + k];

    float lm = act ? l : -1e30f;
#pragma unroll
    for (int off = 32; off >= 1; off >>= 1) lm = fmaxf(lm, __shfl_xor(lm, off, 64));

    float e = act ? expf(l - lm) : 0.f;
    float se = e;
#pragma unroll
    for (int off = 32; off >= 1; off >>= 1) se += __shfl_xor(se, off, 64);

    if (kv) out[(size_t)g * KK + k] = e / se;
}

// ---------------------------------------------------------------------------
extern "C" void kernel_launch(void* const* d_in, const int* in_sizes, int n_in,
                              void* d_out, int out_size, void* d_ws, size_t ws_size,
                              hipStream_t stream) {
    const float* v        = (const float*)d_in[0];
    const float* q        = (const float*)d_in[1];
    const float* box_mask = (const float*)d_in[2];
    const int*   tags     = (const int*)d_in[3];
    const float* w1       = (const float*)d_in[4];
    const float* b1       = (const float*)d_in[5];
    const float* w2       = (const float*)d_in[6];

    unsigned short* w1vT  = (unsigned short*)d_ws;                         // 1 MB
    float* qp      = (float*)((char*)d_ws + 1048576);                      // 6.68 MB
    float* logits  = (float*)((char*)d_ws + 1048576 + 6684672);            // 470 KB
    int*   starts  = (int*)((char*)d_ws + 1048576 + 6684672 + 470016);
    int*   lengths = (int*)((char*)d_ws + 1048576 + 6684672 + 470016 + 1536);
    float* out     = (float*)d_out;

    hipLaunchKernelGGL(prep_w1T, dim3((HH * VDIM) / 256), dim3(256), 0, stream, w1, w1vT);
    hipLaunchKernelGGL(starts_kernel, dim3(1), dim3(512), 0, stream, tags, starts, lengths);
    hipLaunchKernelGGL(qproj_kernel, dim3(NROWS / 16), dim3(256), 0, stream, q, w1, b1, qp);
    hipLaunchKernelGGL(main_gemm, dim3(MM / 64), dim3(256), 0, stream,
                       v, w1vT, qp, w2, logits);
    hipLaunchKernelGGL(softmax_kernel, dim3((BB * SS * TT) / 4), dim3(256), 0, stream,
                       logits, box_mask, starts, lengths, out);
}